// Round 7
// baseline (3262.939 us; speedup 1.0000x reference)
//
#include <hip/hip_runtime.h>
#include <hip/hip_fp16.h>

#define B_SZ 64
#define T_SZ 2048
#define D_SZ 256
#define H_SZ 256
#define G3   768
#define M_SZ (B_SZ * T_SZ) // 131072

typedef _Float16 half2v __attribute__((ext_vector_type(2)));
typedef _Float16 half4v __attribute__((ext_vector_type(4)));
typedef _Float16 half8v __attribute__((ext_vector_type(8)));
typedef float    f32x4  __attribute__((ext_vector_type(4)));

#if defined(__has_attribute)
#  if __has_attribute(amdgpu_agpr_alloc)
#    define NO_AGPR __attribute__((amdgpu_agpr_alloc(0)))
#  else
#    define NO_AGPR
#  endif
#else
#  define NO_AGPR
#endif

static __device__ __forceinline__ float fdot2f(uint a, uint b, float acc) {
#if __has_builtin(__builtin_amdgcn_fdot2)
  return __builtin_amdgcn_fdot2(__builtin_bit_cast(half2v, a),
                                __builtin_bit_cast(half2v, b), acc, false);
#else
  half2v av = __builtin_bit_cast(half2v, a), bv = __builtin_bit_cast(half2v, b);
  acc = fmaf((float)av[0], (float)bv[0], acc);
  acc = fmaf((float)av[1], (float)bv[1], acc);
  return acc;
#endif
}

static __device__ __forceinline__ float h2f(ushort u) {
  return (float)__builtin_bit_cast(_Float16, u);
}
static __device__ __forceinline__ ushort f2h(float x) {
  return __builtin_bit_cast(ushort, (_Float16)x);
}
static __device__ __forceinline__ float fast_rcp(float x) {
  return __builtin_amdgcn_rcpf(x);
}

// ---------- prep 1: Wx f32 -> f16 (GEMM B operand) ----------
__global__ void prep_wx(const float* __restrict__ Wx, ushort* __restrict__ Wxh) {
  int i = blockIdx.x * 256 + threadIdx.x;
  if (i < G3 * D_SZ) Wxh[i] = f2h(Wx[i]);
}

// ---------- prep 2: Wh -> packed f16-pair dwords, dwordx4-coalesced ----------
// gru_rec thread j (0..767) reads uint4 slot s4 (0..31) at (s4*768 + j).
// Slot s4's 4 dwords e=0..3 are h-pairs kp = 4*s4 + e of row j.
__global__ void prep_wq(const float* __restrict__ Wh, uint* __restrict__ Wq) {
  int f = blockIdx.x * 256 + threadIdx.x; // 0 .. 98303
  int e = f & 3;
  int t2 = f >> 2;
  int j = t2 % G3;
  int s4 = t2 / G3;     // 0..31
  int kp = 4 * s4 + e;  // 0..127
  float a = Wh[(size_t)j * D_SZ + 2 * kp];
  float b = Wh[(size_t)j * D_SZ + 2 * kp + 1];
  Wq[f] = (uint)f2h(a) | ((uint)f2h(b) << 16);
}

// ---------- GEMM: xs[m, g] = inputs[m, :] . Wx[g, :] + bx[g], stored f16 ----------
__global__ __launch_bounds__(256) void gemm_x(
    const float* __restrict__ A,   // [M_SZ, 256] f32
    const ushort* __restrict__ Bw, // Wx f16 [768, 256]
    const float* __restrict__ bx,  // [768] f32
    ushort* __restrict__ xs) {     // [M_SZ, 768] f16
  __shared__ _Float16 As[128][72];
  __shared__ _Float16 Bs[256][72];
  const int nt = blockIdx.x, mt = blockIdx.y;
  const int tid = threadIdx.x;
  const int lane = tid & 63, wv = tid >> 6;
  const int wr = (wv >> 1) * 64, wc = (wv & 1) * 128;
  const int l15 = lane & 15, l4 = lane >> 4;
  f32x4 acc[4][8] = {};
  for (int kt = 0; kt < 4; kt++) {
#pragma unroll
    for (int i = 0; i < 8; i++) {
      int f = tid + i * 256;
      int r = f >> 4, c4 = f & 15;
      float4 v = *(const float4*)(A + (size_t)(mt * 128 + r) * D_SZ + kt * 64 + c4 * 4);
      half4v h;
      h[0] = (_Float16)v.x; h[1] = (_Float16)v.y;
      h[2] = (_Float16)v.z; h[3] = (_Float16)v.w;
      *(half4v*)&As[r][c4 * 4] = h;
    }
#pragma unroll
    for (int i = 0; i < 8; i++) {
      int f = tid + i * 256;
      int r = f >> 3, c8 = f & 7;
      uint4 v = *(const uint4*)(Bw + (size_t)(nt * 256 + r) * D_SZ + kt * 64 + c8 * 8);
      *(uint4*)&Bs[r][c8 * 8] = v;
    }
    __syncthreads();
#pragma unroll
    for (int kk = 0; kk < 2; kk++) {
      half8v af[4], bf[8];
#pragma unroll
      for (int m = 0; m < 4; m++)
        af[m] = *(const half8v*)&As[wr + m * 16 + l15][kk * 32 + l4 * 8];
#pragma unroll
      for (int n = 0; n < 8; n++)
        bf[n] = *(const half8v*)&Bs[wc + n * 16 + l15][kk * 32 + l4 * 8];
#pragma unroll
      for (int m = 0; m < 4; m++) {
#pragma unroll
        for (int n = 0; n < 8; n++) {
          acc[m][n] = __builtin_amdgcn_mfma_f32_16x16x32_f16(af[m], bf[n], acc[m][n], 0, 0, 0);
        }
      }
    }
    __syncthreads();
  }
#pragma unroll
  for (int n = 0; n < 8; n++) {
    int col = nt * 256 + wc + n * 16 + l15;
    float bxv = bx[col];
#pragma unroll
    for (int m = 0; m < 4; m++) {
#pragma unroll
      for (int v4 = 0; v4 < 4; v4++) {
        int row = mt * 128 + wr + m * 16 + l4 * 4 + v4;
        xs[(size_t)row * G3 + col] = f2h(acc[m][n][v4] + bxv);
      }
    }
  }
}

// ---------- recurrence: 768 threads, occupancy PINNED to 3 waves/EU ----------
// Thread j owns pre-activation row j. Weight row split: h-pairs 0..119 in
// 30 uint4 registers; h-pairs 120..127 in a persistent LDS copy (wl, stride
// 12 dwords). waves_per_eu(3,3) pins the compiler's occupancy target so the
// arch-VGPR cap is ~170 (not the 2x-min heuristic's ~85 that forced AGPR
// spills + v_accvgpr moves in rounds 2-6). h broadcast from LDS; 2 raw
// barriers/step with lgkmcnt-only waits.
__global__ __launch_bounds__(768)
__attribute__((amdgpu_waves_per_eu(3, 3))) NO_AGPR
void gru_rec(
    const ushort* __restrict__ xs, // [B, T, 768] f16
    const uint* __restrict__ Wq,   // packed per-thread weights
    const float* __restrict__ bh,  // [768]
    const float* __restrict__ hid, // [1, B, 256]
    float* __restrict__ out) {     // [B, T, 256] f32
  const int b = blockIdx.x;
  const int j = threadIdx.x;
  __shared__ alignas(16) ushort h16[H_SZ];
  __shared__ float rs[H_SZ];
  __shared__ float us[H_SZ];
  __shared__ alignas(16) uint wl[G3 * 12]; // per-row 8 dwords used, stride 12 (48B, 16B-aligned)

  // 30 coalesced dwordx4 weight loads -> 120 registers; last 2 slots -> LDS
  uint4 w4[30];
  {
    const uint4* wp = (const uint4*)Wq;
#pragma unroll
    for (int s4 = 0; s4 < 30; s4++) w4[s4] = wp[(size_t)s4 * G3 + j];
    uint4 la = wp[(size_t)30 * G3 + j];
    uint4 lb = wp[(size_t)31 * G3 + j];
    *(uint4*)&wl[j * 12 + 0] = la;
    *(uint4*)&wl[j * 12 + 4] = lb;
  }
  const float bhj = bh[j];
  if (j < H_SZ) h16[j] = f2h(hid[b * H_SZ + j]);
  __syncthreads();

  const ushort* xrow = xs + (size_t)b * T_SZ * G3 + j;
  float* orow = out + (size_t)b * T_SZ * H_SZ;
  const uint4* wlr = (const uint4*)&wl[j * 12];
  ushort xu = xrow[0];

#pragma unroll 1
  for (int t = 0; t < T_SZ; t++) {
    // prefetch next step's x (latency hides under the dot chain)
    ushort xnext = (t + 1 < T_SZ) ? xrow[(size_t)(t + 1) * G3] : (ushort)0;
    float x = h2f(xu);

    // dot: Wh[j,:] . h  (128 dot2; 120 reg-sourced + 8 LDS-sourced)
    float d0 = 0.f, d1 = 0.f, d2 = 0.f, d3 = 0.f;
    const uint4* hq = (const uint4*)h16;
    { // LDS-resident tail first (per-lane reads; latency hides under reg dots)
      uint4 wa = wlr[0], wb = wlr[1];
      uint4 qa = hq[30], qb = hq[31];
      d0 = fdot2f(wa.x, qa.x, d0);
      d1 = fdot2f(wa.y, qa.y, d1);
      d2 = fdot2f(wa.z, qa.z, d2);
      d3 = fdot2f(wa.w, qa.w, d3);
      d0 = fdot2f(wb.x, qb.x, d0);
      d1 = fdot2f(wb.y, qb.y, d1);
      d2 = fdot2f(wb.z, qb.z, d2);
      d3 = fdot2f(wb.w, qb.w, d3);
    }
#pragma unroll
    for (int c = 0; c < 30; c++) {
      uint4 q = hq[c];
      uint4 wv = w4[c];
      d0 = fdot2f(wv.x, q.x, d0);
      d1 = fdot2f(wv.y, q.y, d1);
      d2 = fdot2f(wv.z, q.z, d2);
      d3 = fdot2f(wv.w, q.w, d3);
    }
    float pre = ((d0 + d1) + (d2 + d3)) + bhj;

    if (j < 512) {
      float a = pre + x;                  // x_r + h_r  |  x_u + h_u
      float s = fast_rcp(1.f + __expf(-a));
      if (j < H_SZ) rs[j] = s;
      else          us[j - H_SZ] = s;
    }
    asm volatile("s_waitcnt lgkmcnt(0)" ::: "memory");
    __builtin_amdgcn_s_barrier();

    if (j >= 512) {                       // gate-n threads do the combine
      int i = j - 512;
      float r = rs[i], u = us[i];
      float hold = h2f(h16[i]);
      float arg = x + r * pre;            // x_n + reset*h_n
      float e = __expf(-2.f * fabsf(arg));
      float th = copysignf((1.f - e) * fast_rcp(1.f + e), arg);
      float hn = u * hold + (1.f - u) * th;
      orow[(size_t)t * H_SZ + i] = hn;    // fire-and-forget
      h16[i] = f2h(hn);
    }
    asm volatile("s_waitcnt lgkmcnt(0)" ::: "memory");
    __builtin_amdgcn_s_barrier();
    xu = xnext;
  }
}

extern "C" void kernel_launch(void* const* d_in, const int* in_sizes, int n_in,
                              void* d_out, int out_size, void* d_ws, size_t ws_size,
                              hipStream_t stream) {
  const float* inp = (const float*)d_in[0]; // [B,T,D] f32
  const float* hid = (const float*)d_in[1]; // [1,B,H] f32
  const float* Wx  = (const float*)d_in[2]; // [768,256] f32
  const float* bx  = (const float*)d_in[3]; // [768] f32
  const float* Wh  = (const float*)d_in[4]; // [768,256] f32
  const float* bh  = (const float*)d_in[5]; // [768] f32
  float* out = (float*)d_out;

  // workspace: xs f16 [M_SZ,768] (192 MiB), Wxh f16 (384 KiB), Wq uint (384 KiB)
  char* ws = (char*)d_ws;
  ushort* xs = (ushort*)ws;
  size_t xs_bytes = (size_t)M_SZ * G3 * sizeof(ushort);
  ushort* Wxh = (ushort*)(ws + xs_bytes);
  uint* Wq = (uint*)(ws + xs_bytes + (size_t)G3 * D_SZ * sizeof(ushort));

  prep_wx<<<768, 256, 0, stream>>>(Wx, Wxh);
  prep_wq<<<384, 256, 0, stream>>>(Wh, Wq);
  gemm_x<<<dim3(3, 1024), 256, 0, stream>>>(inp, Wxh, bx, xs);
  gru_rec<<<B_SZ, G3, 0, stream>>>(xs, Wq, bh, hid, out);
}